// Round 13
// baseline (117.146 us; speedup 1.0000x reference)
//
#include <hip/hip_runtime.h>
#include <hip/hip_bf16.h>
#include <stdint.h>

#define D_MODEL 1024
#define NHEADS  16
#define HDIM    64
#define BATCH   2
#define SEQ     2048
#define MROWS   (BATCH*SEQ)   // 4096

typedef __attribute__((ext_vector_type(8))) short  bf16x8;
typedef __attribute__((ext_vector_type(4))) float  f32x4;
typedef __attribute__((ext_vector_type(4))) int    int4v;

__device__ __forceinline__ unsigned short f2bf(float f) {
  unsigned int u = __float_as_uint(f);
  u = (u + 0x7fffu + ((u >> 16) & 1u)) >> 16;   // RNE
  return (unsigned short)u;
}

__device__ __forceinline__ unsigned cvtpk_bf16(float lo, float hi) {
  unsigned r;
  asm("v_cvt_pk_bf16_f32 %0, %1, %2" : "=v"(r) : "v"(lo), "v"(hi));
  return r;
}

__device__ __forceinline__ void gload_lds16(const unsigned short* g, unsigned short* l) {
  __builtin_amdgcn_global_load_lds(
      (const __attribute__((address_space(1))) void*)g,
      (__attribute__((address_space(3))) void*)l,
      16, 0, 0);
}

// chunk-level swizzle for LDS tiles with 128B-periodic rows (8 chunks)
__device__ __forceinline__ int swz_chunk(int row) { return (row + (row >> 3)) & 7; }
// chunk swizzle for 64B-periodic rows (4 chunks)
__device__ __forceinline__ int swz4(int row) { return (row + (row >> 2)) & 3; }
// K-row permutation for attn zero-shuffle P
__device__ __forceinline__ int kperm(int m) {
  return (m & 0x63) | ((m & 0x10) >> 2) | ((m & 0x0C) << 1);
}

// ---------------------------------------------------------------- convert
struct CvtArgs {
  const float* src[7];
  unsigned short* dst[7];
  int n[7];
};

__global__ __launch_bounds__(256) void cvt_all(CvtArgs a) {
  int t = blockIdx.y;
  const float* s = a.src[t];
  unsigned short* d = a.dst[t];
  int n = a.n[t];
  int stride = gridDim.x * blockDim.x * 4;
  for (int i = (blockIdx.x * blockDim.x + threadIdx.x) * 4; i < n; i += stride) {
    float4 v = *(const float4*)(s + i);
    ushort4 o;
    o.x = f2bf(v.x); o.y = f2bf(v.y); o.z = f2bf(v.z); o.w = f2bf(v.w);
    *(ushort4*)(d + i) = o;
  }
}

// ---------------------------------------------------------------- QKV projection
// 256x128 tile, 384 blocks (ALL 256 CUs active; 128 CUs get 2 blocks), 8 waves,
// BK=32, 3-buffer rotation, counted-vmcnt pipeline (3 loads/K-tile -> vmcnt(3)).
// z==0: Q (scaled), z==1: K, z==2: V written TRANSPOSED to [B,H,Dh,S].
__global__ __launch_bounds__(512, 2) void gemm_qkv256(
    const unsigned short* __restrict__ Xq, const unsigned short* __restrict__ Xk,
    const unsigned short* __restrict__ Xv,
    const unsigned short* __restrict__ Wq, const unsigned short* __restrict__ Wk,
    const unsigned short* __restrict__ Wv,
    const float* __restrict__ bq, const float* __restrict__ bk,
    const float* __restrict__ bv,
    unsigned short* __restrict__ oq, unsigned short* __restrict__ ok,
    unsigned short* __restrict__ ov) {
  // 3 x (A 16KB + B 8KB) = 72KB
  __shared__ __align__(16) unsigned short LDS[3 * 12288];

  const int tid  = threadIdx.x;
  const int lane = tid & 63;
  const int w8   = tid >> 6;
  const int wr   = w8 >> 2;         // 0..1 (128-row half)
  const int wc   = w8 & 3;          // 0..3 (32-col group)
  const int g    = lane >> 4;
  const int cl   = lane & 15;

  int fid   = blockIdx.x;           // 0..383
  int xcd   = fid & 7;
  int r_    = fid >> 3;             // 0..47
  int mloc  = r_ / 3;               // 0..15 (m outer within XCD)
  int nzloc = r_ % 3;               // nz innermost -> X-tile L2-hot
  int nz    = xcd * 3 + nzloc;      // 0..23
  int z     = nz >> 3;
  int n0    = (nz & 7) * 128;
  int m0    = mloc * 256;

  const unsigned short* X = (z == 0) ? Xq : (z == 1) ? Xk : Xv;
  const unsigned short* W = (z == 0) ? Wq : (z == 1) ? Wk : Wv;
  const float* bias       = (z == 0) ? bq : (z == 1) ? bk : bv;
  float scale = (z == 0) ? 0.18033688011112042f : 1.0f;   // 1/8 * log2(e)

  const int srow   = tid >> 2;            // 0..127
  const int schunk = tid & 3;
  const int scol   = (schunk ^ swz4(srow)) * 8;   // swz4(srow)==swz4(srow+128)

  auto stageH = [&](int h) {   // even=A-tile (2 loads), odd=B-tile (1 load) of K-tile h>>1
    if (h >= 64) return;
    int t_ = h >> 1, qa = h & 1;
    unsigned short* buf = LDS + (t_ % 3) * 12288;
    if (qa == 0) {
      const unsigned short* src = X + (size_t)(m0 + srow) * D_MODEL + t_ * 32 + scol;
      gload_lds16(src,                          buf + tid * 8);
      gload_lds16(src + (size_t)128 * D_MODEL,  buf + 4096 + tid * 8);
    } else {
      const unsigned short* src = W + (size_t)(n0 + srow) * D_MODEL + t_ * 32 + scol;
      gload_lds16(src, buf + 8192 + tid * 8);
    }
  };

  f32x4 acc[8][2] = {};

  stageH(0); stageH(1); stageH(2); stageH(3);
  asm volatile("s_waitcnt vmcnt(3)" ::: "memory");
  __builtin_amdgcn_s_barrier();
  __builtin_amdgcn_sched_barrier(0);

  for (int t = 0; t < 32; ++t) {
    const unsigned short* Ab = LDS + (t % 3) * 12288;
    const unsigned short* Bb = Ab + 8192;
    bf16x8 af[4], bcache[2];

    // ---------------- phase 0: C-rows 0..63 of this wave's 128-row half
#pragma unroll
    for (int i = 0; i < 4; ++i) {
      int row = wr * 128 + i * 16 + cl;
      af[i] = *(const bf16x8*)((const char*)Ab + row * 64 + ((g ^ swz4(row)) << 4));
    }
#pragma unroll
    for (int j = 0; j < 2; ++j) {
      int row = wc * 32 + j * 16 + cl;
      bcache[j] = *(const bf16x8*)((const char*)Bb + row * 64 + ((g ^ swz4(row)) << 4));
    }
    stageH(2 * t + 4);   // A-tile of K-tile t+2
    __builtin_amdgcn_s_barrier();
    __builtin_amdgcn_sched_barrier(0);
    __builtin_amdgcn_s_setprio(1);
#pragma unroll
    for (int i = 0; i < 4; ++i)
#pragma unroll
      for (int j = 0; j < 2; ++j)
        acc[i][j] = __builtin_amdgcn_mfma_f32_16x16x32_bf16(af[i], bcache[j],
                                                            acc[i][j], 0, 0, 0);
    __builtin_amdgcn_s_setprio(0);
    __builtin_amdgcn_s_barrier();
    __builtin_amdgcn_sched_barrier(0);

    // ---------------- phase 1: C-rows 64..127 (B-frags reused from regs)
#pragma unroll
    for (int i = 0; i < 4; ++i) {
      int row = wr * 128 + (4 + i) * 16 + cl;
      af[i] = *(const bf16x8*)((const char*)Ab + row * 64 + ((g ^ swz4(row)) << 4));
    }
    stageH(2 * t + 5);   // B-tile of K-tile t+2
    __builtin_amdgcn_s_barrier();
    __builtin_amdgcn_sched_barrier(0);
    __builtin_amdgcn_s_setprio(1);
#pragma unroll
    for (int i = 0; i < 4; ++i)
#pragma unroll
      for (int j = 0; j < 2; ++j)
        acc[4 + i][j] = __builtin_amdgcn_mfma_f32_16x16x32_bf16(af[i], bcache[j],
                                                                acc[4 + i][j], 0, 0, 0);
    __builtin_amdgcn_s_setprio(0);
    // K-tile boundary: K-tile t+1's 3 loads must be resident; t+2's 3 may fly.
    if (t < 30) {
      asm volatile("s_waitcnt vmcnt(3)" ::: "memory");
    } else if (t == 30) {
      asm volatile("s_waitcnt vmcnt(0)" ::: "memory");
    }
    __builtin_amdgcn_s_barrier();
    __builtin_amdgcn_sched_barrier(0);
  }

  if (z == 2) {
    // ---- V^T epilogue: vt[(b*1024 + n)][s], 4 r-contiguous s per 8B store
    int b = m0 >> 11;
    int sbase = (m0 & 2047) + wr * 128 + g * 4;
#pragma unroll
    for (int nj = 0; nj < 2; ++nj) {
      int n = n0 + wc * 32 + nj * 16 + cl;
      float bn = bias[n];
      unsigned short* vrow = ov + ((size_t)(b * 1024 + n)) * 2048;
#pragma unroll
      for (int mi = 0; mi < 8; ++mi) {
        int s = sbase + mi * 16;
        uint2 val;
        val.x = cvtpk_bf16(acc[mi][nj][0] + bn, acc[mi][nj][1] + bn);
        val.y = cvtpk_bf16(acc[mi][nj][2] + bn, acc[mi][nj][3] + bn);
        *(uint2*)(vrow + s) = val;
      }
    }
  } else {
    unsigned short* outp = (z == 0) ? oq : ok;
#pragma unroll
    for (int mi = 0; mi < 8; ++mi)
#pragma unroll
      for (int nj = 0; nj < 2; ++nj) {
        int n = n0 + wc * 32 + nj * 16 + cl;
        float bn = bias[n];
        int h = n >> 6, dh = n & 63;
#pragma unroll
        for (int r = 0; r < 4; ++r) {
          int m = m0 + wr * 128 + mi * 16 + g * 4 + r;
          float val = (acc[mi][nj][r] + bn) * scale;
          int b = m >> 11, s = m & 2047;
          outp[(((size_t)(b * NHEADS + h)) * SEQ + s) * HDIM + dh] = f2bf(val);
        }
      }
  }
}

// ---------------------------------------------------------------- output projection
// 128x128 tile, 8 waves (2x4), BK=32, 3-buffer rotation, counted vmcnt.
__global__ __launch_bounds__(512) void gemm_out2(
    const unsigned short* __restrict__ Xc, const unsigned short* __restrict__ Wo,
    const float* __restrict__ bo, float* __restrict__ out) {
  __shared__ __align__(16) unsigned short LDS[3 * 8192];   // 48KB

  const int tid  = threadIdx.x;
  const int lane = tid & 63;
  const int w8   = tid >> 6;
  const int wr   = w8 >> 2;         // 0..1
  const int wc   = w8 & 3;          // 0..3
  const int g    = lane >> 4;
  const int cl   = lane & 15;

  int fid = blockIdx.x;                       // 0..255
  int sid = (fid & 7) * 32 + (fid >> 3);      // XCD-contiguous
  int m0 = (sid >> 3) * 128;
  int n0 = (sid & 7) * 128;

  const int srow   = tid >> 2;            // 0..127
  const int scol   = ((tid & 3) ^ swz4(srow)) * 8;

  auto stage_ = [&](int t_) {
    if (t_ >= 32) return;
    unsigned short* buf = LDS + (t_ % 3) * 8192;
    const unsigned short* sa = Xc + (size_t)(m0 + srow) * D_MODEL + t_ * 32 + scol;
    const unsigned short* sb = Wo + (size_t)(n0 + srow) * D_MODEL + t_ * 32 + scol;
    gload_lds16(sa, buf + tid * 8);
    gload_lds16(sb, buf + 4096 + tid * 8);
  };

  f32x4 acc[4][2] = {};

  stage_(0); stage_(1);
  asm volatile("s_waitcnt vmcnt(2)" ::: "memory");
  __builtin_amdgcn_s_barrier();
  __builtin_amdgcn_sched_barrier(0);

  for (int t = 0; t < 32; ++t) {
    const unsigned short* Ab = LDS + (t % 3) * 8192;
    const unsigned short* Bb = Ab + 4096;
    bf16x8 af[4], bf[2];
#pragma unroll
    for (int i = 0; i < 4; ++i) {
      int row = wr * 64 + i * 16 + cl;
      af[i] = *(const bf16x8*)((const char*)Ab + row * 64 + ((g ^ swz4(row)) << 4));
    }
#pragma unroll
    for (int j = 0; j < 2; ++j) {
      int row = wc * 32 + j * 16 + cl;
      bf[j] = *(const bf16x8*)((const char*)Bb + row * 64 + ((g ^ swz4(row)) << 4));
    }
    stage_(t + 2);
    __builtin_amdgcn_s_barrier();
    __builtin_amdgcn_sched_barrier(0);
    __builtin_amdgcn_s_setprio(1);
#pragma unroll
    for (int i = 0; i < 4; ++i)
#pragma unroll
      for (int j = 0; j < 2; ++j)
        acc[i][j] = __builtin_amdgcn_mfma_f32_16x16x32_bf16(af[i], bf[j],
                                                            acc[i][j], 0, 0, 0);
    __builtin_amdgcn_s_setprio(0);
    if (t < 30) {
      asm volatile("s_waitcnt vmcnt(2)" ::: "memory");
    } else if (t == 30) {
      asm volatile("s_waitcnt vmcnt(0)" ::: "memory");
    }
    __builtin_amdgcn_s_barrier();
    __builtin_amdgcn_sched_barrier(0);
  }

#pragma unroll
  for (int mi = 0; mi < 4; ++mi)
#pragma unroll
    for (int nj = 0; nj < 2; ++nj) {
      int n = n0 + wc * 32 + nj * 16 + cl;
      float bn = bo[n];
#pragma unroll
      for (int r = 0; r < 4; ++r) {
        int m = m0 + wr * 64 + mi * 16 + g * 4 + r;
        out[(size_t)m * D_MODEL + n] = acc[mi][nj][r] + bn;
      }
    }
}

// ---------------------------------------------------------------- flash attention
// grid (32,16): x=bh, y=q-tile. 4 waves x 32 q. KVBLK=128, swapped QK^T,
// zero-shuffle P, direct exp2 (no max; scale cancels), ones-column row-sum.
__global__ __launch_bounds__(256, 2) void attn(
    const unsigned short* __restrict__ q, const unsigned short* __restrict__ k,
    const unsigned short* __restrict__ vt, unsigned short* __restrict__ ctx) {
  __shared__ __align__(16) unsigned short K0[128 * 64], V0[64 * 128];
  __shared__ __align__(16) unsigned short K1[128 * 64], V1[64 * 128];

  const int tid  = threadIdx.x;
  const int lane = tid & 63;
  const int wv   = tid >> 6;
  const int g    = lane >> 4;
  const int cl   = lane & 15;

  const int bh = blockIdx.x;
  const int qt = blockIdx.y;

  const unsigned short* qb  = q  + (size_t)bh * SEQ * HDIM;
  const unsigned short* kb  = k  + (size_t)bh * SEQ * HDIM;
  const unsigned short* vbt = vt + (size_t)bh * HDIM * SEQ;

  bf16x8 qf[2][2];
  {
    int qbase = qt * 128 + wv * 32;
#pragma unroll
    for (int qh = 0; qh < 2; ++qh) {
      const unsigned short* qp = qb + (size_t)(qbase + qh * 16 + cl) * HDIM + 8 * g;
      qf[qh][0] = *(const bf16x8*)(qp);
      qf[qh][1] = *(const bf16x8*)(qp + 32);
    }
  }

  const int srowK = tid >> 3;
  const int swzK  = swz_chunk(srowK);
  const int vrow  = tid >> 4;
  const int swzV  = swz_chunk(vrow);
  const int ldst  = tid * 16;

  f32x4 acc0[4] = {}, acc1[4] = {};
  f32x4 accs0 = {}, accs1 = {};
  const int4v onesi = {0x3F803F80, 0x3F803F80, 0x3F803F80, 0x3F803F80};
  const bf16x8 onesb = __builtin_bit_cast(bf16x8, onesi);

  auto stageK_ = [&](int t, unsigned short* Kb) {
    const unsigned short* kt_ = kb + (size_t)t * 128 * HDIM;
#pragma unroll
    for (int c = 0; c < 4; ++c) {
      int row  = srowK + 32 * c;
      int col  = ((tid & 7) ^ swzK ^ ((c & 1) << 2)) * 8;
      gload_lds16(kt_ + (size_t)kperm(row) * HDIM + col,
                  (unsigned short*)((char*)Kb + ldst + c * 4096));
    }
  };
  auto stageV_ = [&](int t, unsigned short* Vb) {
    const unsigned short* vt_ = vbt + t * 128;
#pragma unroll
    for (int c = 0; c < 4; ++c) {
      int row = vrow + 16 * c;
      int sw  = (swzV + 2 * c) & 7;
      int col = (((tid & 7) ^ sw) | (tid & 8)) * 8;
      gload_lds16(vt_ + (size_t)row * SEQ + col,
                  (unsigned short*)((char*)Vb + ldst + c * 4096));
    }
  };

  f32x4 sc[8][2];

  auto qk = [&](const unsigned short* Kb) {
#pragma unroll
    for (int ni = 0; ni < 8; ++ni) { sc[ni][0] = f32x4{}; sc[ni][1] = f32x4{}; }
    __builtin_amdgcn_s_setprio(1);
#pragma unroll
    for (int kc = 0; kc < 2; ++kc)
#pragma unroll
      for (int ni = 0; ni < 8; ++ni) {
        int row  = ni * 16 + cl;
        int byte = row * 128 + (((kc * 4 + g) ^ swz_chunk(row)) << 4);
        bf16x8 kf = *(const bf16x8*)((const char*)Kb + byte);
        sc[ni][0] = __builtin_amdgcn_mfma_f32_16x16x32_bf16(kf, qf[0][kc], sc[ni][0], 0, 0, 0);
        sc[ni][1] = __builtin_amdgcn_mfma_f32_16x16x32_bf16(kf, qf[1][kc], sc[ni][1], 0, 0, 0);
      }
    __builtin_amdgcn_s_setprio(0);
  };

  auto smpack = [&](int4v (&pa0)[4], int4v (&pa1)[4]) {
#pragma unroll
    for (int qh = 0; qh < 2; ++qh)
#pragma unroll
      for (int ni = 0; ni < 8; ++ni)
#pragma unroll
        for (int r = 0; r < 4; ++r)
          sc[ni][qh][r] = __builtin_amdgcn_exp2f(sc[ni][qh][r]);
#pragma unroll
    for (int kcp = 0; kcp < 4; ++kcp) {
      pa0[kcp][0] = (int)cvtpk_bf16(sc[2 * kcp][0][0], sc[2 * kcp][0][1]);
      pa0[kcp][1] = (int)cvtpk_bf16(sc[2 * kcp][0][2], sc[2 * kcp][0][3]);
      pa0[kcp][2] = (int)cvtpk_bf16(sc[2 * kcp + 1][0][0], sc[2 * kcp + 1][0][1]);
      pa0[kcp][3] = (int)cvtpk_bf16(sc[2 * kcp + 1][0][2], sc[2 * kcp + 1][0][3]);
      pa1[kcp][0] = (int)cvtpk_bf16(sc[2 * kcp][1][0], sc[2 * kcp][1][1]);
      pa1[kcp][1] = (int)cvtpk_bf16(sc[2 * kcp][1][2], sc[2 * kcp][1][3]);
      pa1[kcp][2] = (int)cvtpk_bf16(sc[2 * kcp + 1][1][0], sc[2 * kcp + 1][1][1]);
      pa1[kcp][3] = (int)cvtpk_bf16(sc[2 * kcp + 1][1][2], sc[2 * kcp + 1][1][3]);
    }
  };

  auto pv = [&](const unsigned short* Vb, int4v (&pa0)[4], int4v (&pa1)[4]) {
    __builtin_amdgcn_s_setprio(1);
#pragma unroll
    for (int kcp = 0; kcp < 4; ++kcp) {
      bf16x8 a0 = __builtin_bit_cast(bf16x8, pa0[kcp]);
      bf16x8 a1 = __builtin_bit_cast(bf16x8, pa1[kcp]);
#pragma unroll
      for (int nd = 0; nd < 4; ++nd) {
        int row = nd * 16 + cl;
        int c   = kcp * 4 + g;
        int byte = row * 256 + ((((c & 7) ^ swz_chunk(row)) | (c & 8)) << 4);
        bf16x8 vf = *(const bf16x8*)((const char*)Vb + byte);
        acc0[nd] = __builtin_amdgcn_mfma_f32_16x16x32_bf16(a0, vf, acc0[nd], 0, 0, 0);
        acc1[nd] = __builtin_amdgcn_mfma_f32_16x16x32_bf16(a1, vf, acc1[nd], 0, 0, 0);
      }
      accs0 = __builtin_amdgcn_mfma_f32_16x16x32_bf16(a0, onesb, accs0, 0, 0, 0);
      accs1 = __builtin_amdgcn_mfma_f32_16x16x32_bf16(a1, onesb, accs1, 0, 0, 0);
    }
    __builtin_amdgcn_s_setprio(0);
  };

  const int NT = SEQ / 128;   // 16
  stageK_(0, K0);
  stageV_(0, V0);
  __syncthreads();
  stageK_(1, K1);
  qk(K0);
  for (int i = 0; i < NT; ++i) {
    int4v pa0[4], pa1[4];
    smpack(pa0, pa1);
    __syncthreads();
    if (i + 2 < NT) stageK_(i + 2, (i & 1) ? K1 : K0);
    if (i + 1 < NT) stageV_(i + 1, (i & 1) ? V0 : V1);
    if (i + 1 < NT) qk((i & 1) ? K0 : K1);
    pv((i & 1) ? V1 : V0, pa0, pa1);
  }

  int b = bh >> 4, h = bh & 15;
#pragma unroll
  for (int r = 0; r < 4; ++r) {
    float i0 = 1.0f / accs0[r];
    float i1 = 1.0f / accs1[r];
#pragma unroll
    for (int qh = 0; qh < 2; ++qh) {
      int srow_o = qt * 128 + wv * 32 + qh * 16 + g * 4 + r;
      float iv = qh ? i1 : i0;
#pragma unroll
      for (int nd = 0; nd < 4; ++nd) {
        int d = nd * 16 + cl;
        float val = (qh ? acc1[nd][r] : acc0[nd][r]) * iv;
        ctx[(((size_t)(b * SEQ + srow_o)) * NHEADS + h) * HDIM + d] = f2bf(val);
      }
    }
  }
}

// ---------------------------------------------------------------- launch
extern "C" void kernel_launch(void* const* d_in, const int* in_sizes, int n_in,
                              void* d_out, int out_size, void* d_ws, size_t ws_size,
                              hipStream_t stream) {
  (void)in_sizes; (void)n_in; (void)out_size; (void)ws_size;
  const float* query = (const float*)d_in[0];
  const float* key_  = (const float*)d_in[1];
  const float* value = (const float*)d_in[2];
  const float* Wq = (const float*)d_in[3];
  const float* bq = (const float*)d_in[4];
  const float* Wk = (const float*)d_in[5];
  const float* bk = (const float*)d_in[6];
  const float* Wv = (const float*)d_in[7];
  const float* bv = (const float*)d_in[8];
  const float* Wo = (const float*)d_in[9];
  const float* bo = (const float*)d_in[10];
  float* out = (float*)d_out;

  unsigned short* w = (unsigned short*)d_ws;
  const size_t NA = (size_t)MROWS * D_MODEL;    // 4M elems
  const size_t NW = (size_t)D_MODEL * D_MODEL;  // 1M elems
  unsigned short* Xq  = w;
  unsigned short* Xk  = Xq + NA;
  unsigned short* Xv  = Xk + NA;
  unsigned short* Wqb = Xv + NA;
  unsigned short* Wkb = Wqb + NW;
  unsigned short* Wvb = Wkb + NW;
  unsigned short* Wob = Wvb + NW;
  unsigned short* qs  = Wob + NW;     // [B,H,S,Dh]
  unsigned short* ks  = qs + NA;
  unsigned short* vtb = ks + NA;      // [B,H,Dh,S]  (written directly by gemm_qkv256)
  unsigned short* cx  = vtb + NA;     // [B,S,D]

  CvtArgs ca;
  ca.src[0] = query; ca.dst[0] = Xq;  ca.n[0] = (int)NA;
  ca.src[1] = key_;  ca.dst[1] = Xk;  ca.n[1] = (int)NA;
  ca.src[2] = value; ca.dst[2] = Xv;  ca.n[2] = (int)NA;
  ca.src[3] = Wq;    ca.dst[3] = Wqb; ca.n[3] = (int)NW;
  ca.src[4] = Wk;    ca.dst[4] = Wkb; ca.n[4] = (int)NW;
  ca.src[5] = Wv;    ca.dst[5] = Wvb; ca.n[5] = (int)NW;
  ca.src[6] = Wo;    ca.dst[6] = Wob; ca.n[6] = (int)NW;

  cvt_all<<<dim3(256, 7, 1), 256, 0, stream>>>(ca);
  gemm_qkv256<<<dim3(384, 1, 1), 512, 0, stream>>>(Xq, Xk, Xv, Wqb, Wkb, Wvb,
                                                   bq, bk, bv, qs, ks, vtb);
  attn<<<dim3(32, 16, 1), 256, 0, stream>>>(qs, ks, vtb, cx);
  gemm_out2<<<dim3(256, 1, 1), 512, 0, stream>>>(cx, Wob, bo, out);
}

// Round 14
// 115.226 us; speedup vs baseline: 1.0167x; 1.0167x over previous
//
#include <hip/hip_runtime.h>
#include <hip/hip_bf16.h>
#include <stdint.h>

#define D_MODEL 1024
#define NHEADS  16
#define HDIM    64
#define BATCH   2
#define SEQ     2048
#define MROWS   (BATCH*SEQ)   // 4096

typedef __attribute__((ext_vector_type(8))) short  bf16x8;
typedef __attribute__((ext_vector_type(4))) float  f32x4;
typedef __attribute__((ext_vector_type(4))) int    int4v;

__device__ __forceinline__ unsigned short f2bf(float f) {
  unsigned int u = __float_as_uint(f);
  u = (u + 0x7fffu + ((u >> 16) & 1u)) >> 16;   // RNE
  return (unsigned short)u;
}

__device__ __forceinline__ unsigned cvtpk_bf16(float lo, float hi) {
  unsigned r;
  asm("v_cvt_pk_bf16_f32 %0, %1, %2" : "=v"(r) : "v"(lo), "v"(hi));
  return r;
}

__device__ __forceinline__ void gload_lds16(const unsigned short* g, unsigned short* l) {
  __builtin_amdgcn_global_load_lds(
      (const __attribute__((address_space(1))) void*)g,
      (__attribute__((address_space(3))) void*)l,
      16, 0, 0);
}

// chunk-level swizzle for LDS tiles with 128B-periodic rows (8 chunks)
__device__ __forceinline__ int swz_chunk(int row) { return (row + (row >> 3)) & 7; }
// chunk swizzle for 64B-periodic rows (4 chunks)
__device__ __forceinline__ int swz4(int row) { return (row + (row >> 2)) & 3; }
// K-row permutation for attn zero-shuffle P
__device__ __forceinline__ int kperm(int m) {
  return (m & 0x63) | ((m & 0x10) >> 2) | ((m & 0x0C) << 1);
}

// ---------------------------------------------------------------- convert
struct CvtArgs {
  const float* src[7];
  unsigned short* dst[7];
  int n[7];
};

__global__ __launch_bounds__(256) void cvt_all(CvtArgs a) {
  int t = blockIdx.y;
  const float* s = a.src[t];
  unsigned short* d = a.dst[t];
  int n = a.n[t];
  int stride = gridDim.x * blockDim.x * 4;
  for (int i = (blockIdx.x * blockDim.x + threadIdx.x) * 4; i < n; i += stride) {
    float4 v = *(const float4*)(s + i);
    ushort4 o;
    o.x = f2bf(v.x); o.y = f2bf(v.y); o.z = f2bf(v.z); o.w = f2bf(v.w);
    *(ushort4*)(d + i) = o;
  }
}

// ---------------------------------------------------------------- QKV projection
// EXACT gemm_out2 structure: 128x128 tile, 8 waves (2x4), BK=32, 3-buffer
// rotation, counted vmcnt(2). Fused over z: 768 blocks, reuse-aware XCD map
// (3 (z,n)-panels per XCD, nz innermost -> W L2-resident, X-tile hot).
// z==0: Q (scaled), z==1: K, z==2: V written TRANSPOSED to [B,H,Dh,S].
__global__ __launch_bounds__(512) void gemm_qkv128(
    const unsigned short* __restrict__ Xq, const unsigned short* __restrict__ Xk,
    const unsigned short* __restrict__ Xv,
    const unsigned short* __restrict__ Wq, const unsigned short* __restrict__ Wk,
    const unsigned short* __restrict__ Wv,
    const float* __restrict__ bq, const float* __restrict__ bk,
    const float* __restrict__ bv,
    unsigned short* __restrict__ oq, unsigned short* __restrict__ ok,
    unsigned short* __restrict__ ov) {
  __shared__ __align__(16) unsigned short LDS[3 * 8192];   // 48KB

  const int tid  = threadIdx.x;
  const int lane = tid & 63;
  const int w8   = tid >> 6;
  const int wr   = w8 >> 2;         // 0..1 (64-row half)
  const int wc   = w8 & 3;          // 0..3 (32-col group)
  const int g    = lane >> 4;
  const int cl   = lane & 15;

  int fid   = blockIdx.x;           // 0..767
  int xcd   = fid & 7;
  int r_    = fid >> 3;             // 0..95
  int mloc  = r_ / 3;               // 0..31 (m outer within XCD)
  int nzloc = r_ % 3;               // nz innermost -> X-tile L2-hot
  int nz    = xcd * 3 + nzloc;      // 0..23
  int z     = nz >> 3;
  int n0    = (nz & 7) * 128;
  int m0    = mloc * 128;

  const unsigned short* X = (z == 0) ? Xq : (z == 1) ? Xk : Xv;
  const unsigned short* W = (z == 0) ? Wq : (z == 1) ? Wk : Wv;
  const float* bias       = (z == 0) ? bq : (z == 1) ? bk : bv;
  float scale = (z == 0) ? 0.18033688011112042f : 1.0f;   // 1/8 * log2(e)

  const int srow = tid >> 2;            // 0..127
  const int scol = ((tid & 3) ^ swz4(srow)) * 8;

  auto stage_ = [&](int t_) {
    if (t_ >= 32) return;
    unsigned short* buf = LDS + (t_ % 3) * 8192;
    const unsigned short* sa = X + (size_t)(m0 + srow) * D_MODEL + t_ * 32 + scol;
    const unsigned short* sb = W + (size_t)(n0 + srow) * D_MODEL + t_ * 32 + scol;
    gload_lds16(sa, buf + tid * 8);
    gload_lds16(sb, buf + 4096 + tid * 8);
  };

  f32x4 acc[4][2] = {};

  stage_(0); stage_(1);
  asm volatile("s_waitcnt vmcnt(2)" ::: "memory");
  __builtin_amdgcn_s_barrier();
  __builtin_amdgcn_sched_barrier(0);

  for (int t = 0; t < 32; ++t) {
    const unsigned short* Ab = LDS + (t % 3) * 8192;
    const unsigned short* Bb = Ab + 4096;
    bf16x8 af[4], bfr[2];
#pragma unroll
    for (int i = 0; i < 4; ++i) {
      int row = wr * 64 + i * 16 + cl;
      af[i] = *(const bf16x8*)((const char*)Ab + row * 64 + ((g ^ swz4(row)) << 4));
    }
#pragma unroll
    for (int j = 0; j < 2; ++j) {
      int row = wc * 32 + j * 16 + cl;
      bfr[j] = *(const bf16x8*)((const char*)Bb + row * 64 + ((g ^ swz4(row)) << 4));
    }
    stage_(t + 2);
    __builtin_amdgcn_s_barrier();
    __builtin_amdgcn_sched_barrier(0);
    __builtin_amdgcn_s_setprio(1);
#pragma unroll
    for (int i = 0; i < 4; ++i)
#pragma unroll
      for (int j = 0; j < 2; ++j)
        acc[i][j] = __builtin_amdgcn_mfma_f32_16x16x32_bf16(af[i], bfr[j],
                                                            acc[i][j], 0, 0, 0);
    __builtin_amdgcn_s_setprio(0);
    if (t < 30) {
      asm volatile("s_waitcnt vmcnt(2)" ::: "memory");
    } else if (t == 30) {
      asm volatile("s_waitcnt vmcnt(0)" ::: "memory");
    }
    __builtin_amdgcn_s_barrier();
    __builtin_amdgcn_sched_barrier(0);
  }

  if (z == 2) {
    // ---- V^T epilogue: vt[(b*1024 + n)][s], 4 r-contiguous s per 8B store
    int b = m0 >> 11;
    int sbase = (m0 & 2047) + wr * 64 + g * 4;
#pragma unroll
    for (int nj = 0; nj < 2; ++nj) {
      int n = n0 + wc * 32 + nj * 16 + cl;
      float bn = bias[n];
      unsigned short* vrow = ov + ((size_t)(b * 1024 + n)) * 2048;
#pragma unroll
      for (int mi = 0; mi < 4; ++mi) {
        int s = sbase + mi * 16;
        uint2 val;
        val.x = cvtpk_bf16(acc[mi][nj][0] + bn, acc[mi][nj][1] + bn);
        val.y = cvtpk_bf16(acc[mi][nj][2] + bn, acc[mi][nj][3] + bn);
        *(uint2*)(vrow + s) = val;
      }
    }
  } else {
    unsigned short* outp = (z == 0) ? oq : ok;
#pragma unroll
    for (int mi = 0; mi < 4; ++mi)
#pragma unroll
      for (int nj = 0; nj < 2; ++nj) {
        int n = n0 + wc * 32 + nj * 16 + cl;
        float bn = bias[n];
        int h = n >> 6, dh = n & 63;
#pragma unroll
        for (int r = 0; r < 4; ++r) {
          int m = m0 + wr * 64 + mi * 16 + g * 4 + r;
          float val = (acc[mi][nj][r] + bn) * scale;
          int b = m >> 11, s = m & 2047;
          outp[(((size_t)(b * NHEADS + h)) * SEQ + s) * HDIM + dh] = f2bf(val);
        }
      }
  }
}

// ---------------------------------------------------------------- output projection
// 128x128 tile, 8 waves (2x4), BK=32, 3-buffer rotation, counted vmcnt.
__global__ __launch_bounds__(512) void gemm_out2(
    const unsigned short* __restrict__ Xc, const unsigned short* __restrict__ Wo,
    const float* __restrict__ bo, float* __restrict__ out) {
  __shared__ __align__(16) unsigned short LDS[3 * 8192];   // 48KB

  const int tid  = threadIdx.x;
  const int lane = tid & 63;
  const int w8   = tid >> 6;
  const int wr   = w8 >> 2;         // 0..1
  const int wc   = w8 & 3;          // 0..3
  const int g    = lane >> 4;
  const int cl   = lane & 15;

  int fid = blockIdx.x;                       // 0..255
  int sid = (fid & 7) * 32 + (fid >> 3);      // XCD-contiguous
  int m0 = (sid >> 3) * 128;
  int n0 = (sid & 7) * 128;

  const int srow   = tid >> 2;            // 0..127
  const int scol   = ((tid & 3) ^ swz4(srow)) * 8;

  auto stage_ = [&](int t_) {
    if (t_ >= 32) return;
    unsigned short* buf = LDS + (t_ % 3) * 8192;
    const unsigned short* sa = Xc + (size_t)(m0 + srow) * D_MODEL + t_ * 32 + scol;
    const unsigned short* sb = Wo + (size_t)(n0 + srow) * D_MODEL + t_ * 32 + scol;
    gload_lds16(sa, buf + tid * 8);
    gload_lds16(sb, buf + 4096 + tid * 8);
  };

  f32x4 acc[4][2] = {};

  stage_(0); stage_(1);
  asm volatile("s_waitcnt vmcnt(2)" ::: "memory");
  __builtin_amdgcn_s_barrier();
  __builtin_amdgcn_sched_barrier(0);

  for (int t = 0; t < 32; ++t) {
    const unsigned short* Ab = LDS + (t % 3) * 8192;
    const unsigned short* Bb = Ab + 4096;
    bf16x8 af[4], bf[2];
#pragma unroll
    for (int i = 0; i < 4; ++i) {
      int row = wr * 64 + i * 16 + cl;
      af[i] = *(const bf16x8*)((const char*)Ab + row * 64 + ((g ^ swz4(row)) << 4));
    }
#pragma unroll
    for (int j = 0; j < 2; ++j) {
      int row = wc * 32 + j * 16 + cl;
      bf[j] = *(const bf16x8*)((const char*)Bb + row * 64 + ((g ^ swz4(row)) << 4));
    }
    stage_(t + 2);
    __builtin_amdgcn_s_barrier();
    __builtin_amdgcn_sched_barrier(0);
    __builtin_amdgcn_s_setprio(1);
#pragma unroll
    for (int i = 0; i < 4; ++i)
#pragma unroll
      for (int j = 0; j < 2; ++j)
        acc[i][j] = __builtin_amdgcn_mfma_f32_16x16x32_bf16(af[i], bf[j],
                                                            acc[i][j], 0, 0, 0);
    __builtin_amdgcn_s_setprio(0);
    if (t < 30) {
      asm volatile("s_waitcnt vmcnt(2)" ::: "memory");
    } else if (t == 30) {
      asm volatile("s_waitcnt vmcnt(0)" ::: "memory");
    }
    __builtin_amdgcn_s_barrier();
    __builtin_amdgcn_sched_barrier(0);
  }

#pragma unroll
  for (int mi = 0; mi < 4; ++mi)
#pragma unroll
    for (int nj = 0; nj < 2; ++nj) {
      int n = n0 + wc * 32 + nj * 16 + cl;
      float bn = bo[n];
#pragma unroll
      for (int r = 0; r < 4; ++r) {
        int m = m0 + wr * 64 + mi * 16 + g * 4 + r;
        out[(size_t)m * D_MODEL + n] = acc[mi][nj][r] + bn;
      }
    }
}

// ---------------------------------------------------------------- flash attention
// grid (32,16): x=bh, y=q-tile. 4 waves x 32 q. KVBLK=128, swapped QK^T,
// zero-shuffle P, direct exp2 (no max; scale cancels), ones-column row-sum.
__global__ __launch_bounds__(256, 2) void attn(
    const unsigned short* __restrict__ q, const unsigned short* __restrict__ k,
    const unsigned short* __restrict__ vt, unsigned short* __restrict__ ctx) {
  __shared__ __align__(16) unsigned short K0[128 * 64], V0[64 * 128];
  __shared__ __align__(16) unsigned short K1[128 * 64], V1[64 * 128];

  const int tid  = threadIdx.x;
  const int lane = tid & 63;
  const int wv   = tid >> 6;
  const int g    = lane >> 4;
  const int cl   = lane & 15;

  const int bh = blockIdx.x;
  const int qt = blockIdx.y;

  const unsigned short* qb  = q  + (size_t)bh * SEQ * HDIM;
  const unsigned short* kb  = k  + (size_t)bh * SEQ * HDIM;
  const unsigned short* vbt = vt + (size_t)bh * HDIM * SEQ;

  bf16x8 qf[2][2];
  {
    int qbase = qt * 128 + wv * 32;
#pragma unroll
    for (int qh = 0; qh < 2; ++qh) {
      const unsigned short* qp = qb + (size_t)(qbase + qh * 16 + cl) * HDIM + 8 * g;
      qf[qh][0] = *(const bf16x8*)(qp);
      qf[qh][1] = *(const bf16x8*)(qp + 32);
    }
  }

  const int srowK = tid >> 3;
  const int swzK  = swz_chunk(srowK);
  const int vrow  = tid >> 4;
  const int swzV  = swz_chunk(vrow);
  const int ldst  = tid * 16;

  f32x4 acc0[4] = {}, acc1[4] = {};
  f32x4 accs0 = {}, accs1 = {};
  const int4v onesi = {0x3F803F80, 0x3F803F80, 0x3F803F80, 0x3F803F80};
  const bf16x8 onesb = __builtin_bit_cast(bf16x8, onesi);

  auto stageK_ = [&](int t, unsigned short* Kb) {
    const unsigned short* kt_ = kb + (size_t)t * 128 * HDIM;
#pragma unroll
    for (int c = 0; c < 4; ++c) {
      int row  = srowK + 32 * c;
      int col  = ((tid & 7) ^ swzK ^ ((c & 1) << 2)) * 8;
      gload_lds16(kt_ + (size_t)kperm(row) * HDIM + col,
                  (unsigned short*)((char*)Kb + ldst + c * 4096));
    }
  };
  auto stageV_ = [&](int t, unsigned short* Vb) {
    const unsigned short* vt_ = vbt + t * 128;
#pragma unroll
    for (int c = 0; c < 4; ++c) {
      int row = vrow + 16 * c;
      int sw  = (swzV + 2 * c) & 7;
      int col = (((tid & 7) ^ sw) | (tid & 8)) * 8;
      gload_lds16(vt_ + (size_t)row * SEQ + col,
                  (unsigned short*)((char*)Vb + ldst + c * 4096));
    }
  };

  f32x4 sc[8][2];

  auto qk = [&](const unsigned short* Kb) {
#pragma unroll
    for (int ni = 0; ni < 8; ++ni) { sc[ni][0] = f32x4{}; sc[ni][1] = f32x4{}; }
    __builtin_amdgcn_s_setprio(1);
#pragma unroll
    for (int kc = 0; kc < 2; ++kc)
#pragma unroll
      for (int ni = 0; ni < 8; ++ni) {
        int row  = ni * 16 + cl;
        int byte = row * 128 + (((kc * 4 + g) ^ swz_chunk(row)) << 4);
        bf16x8 kf = *(const bf16x8*)((const char*)Kb + byte);
        sc[ni][0] = __builtin_amdgcn_mfma_f32_16x16x32_bf16(kf, qf[0][kc], sc[ni][0], 0, 0, 0);
        sc[ni][1] = __builtin_amdgcn_mfma_f32_16x16x32_bf16(kf, qf[1][kc], sc[ni][1], 0, 0, 0);
      }
    __builtin_amdgcn_s_setprio(0);
  };

  auto smpack = [&](int4v (&pa0)[4], int4v (&pa1)[4]) {
#pragma unroll
    for (int qh = 0; qh < 2; ++qh)
#pragma unroll
      for (int ni = 0; ni < 8; ++ni)
#pragma unroll
        for (int r = 0; r < 4; ++r)
          sc[ni][qh][r] = __builtin_amdgcn_exp2f(sc[ni][qh][r]);
#pragma unroll
    for (int kcp = 0; kcp < 4; ++kcp) {
      pa0[kcp][0] = (int)cvtpk_bf16(sc[2 * kcp][0][0], sc[2 * kcp][0][1]);
      pa0[kcp][1] = (int)cvtpk_bf16(sc[2 * kcp][0][2], sc[2 * kcp][0][3]);
      pa0[kcp][2] = (int)cvtpk_bf16(sc[2 * kcp + 1][0][0], sc[2 * kcp + 1][0][1]);
      pa0[kcp][3] = (int)cvtpk_bf16(sc[2 * kcp + 1][0][2], sc[2 * kcp + 1][0][3]);
      pa1[kcp][0] = (int)cvtpk_bf16(sc[2 * kcp][1][0], sc[2 * kcp][1][1]);
      pa1[kcp][1] = (int)cvtpk_bf16(sc[2 * kcp][1][2], sc[2 * kcp][1][3]);
      pa1[kcp][2] = (int)cvtpk_bf16(sc[2 * kcp + 1][1][0], sc[2 * kcp + 1][1][1]);
      pa1[kcp][3] = (int)cvtpk_bf16(sc[2 * kcp + 1][1][2], sc[2 * kcp + 1][1][3]);
    }
  };

  auto pv = [&](const unsigned short* Vb, int4v (&pa0)[4], int4v (&pa1)[4]) {
    __builtin_amdgcn_s_setprio(1);
#pragma unroll
    for (int kcp = 0; kcp < 4; ++kcp) {
      bf16x8 a0 = __builtin_bit_cast(bf16x8, pa0[kcp]);
      bf16x8 a1 = __builtin_bit_cast(bf16x8, pa1[kcp]);
#pragma unroll
      for (int nd = 0; nd < 4; ++nd) {
        int row = nd * 16 + cl;
        int c   = kcp * 4 + g;
        int byte = row * 256 + ((((c & 7) ^ swz_chunk(row)) | (c & 8)) << 4);
        bf16x8 vf = *(const bf16x8*)((const char*)Vb + byte);
        acc0[nd] = __builtin_amdgcn_mfma_f32_16x16x32_bf16(a0, vf, acc0[nd], 0, 0, 0);
        acc1[nd] = __builtin_amdgcn_mfma_f32_16x16x32_bf16(a1, vf, acc1[nd], 0, 0, 0);
      }
      accs0 = __builtin_amdgcn_mfma_f32_16x16x32_bf16(a0, onesb, accs0, 0, 0, 0);
      accs1 = __builtin_amdgcn_mfma_f32_16x16x32_bf16(a1, onesb, accs1, 0, 0, 0);
    }
    __builtin_amdgcn_s_setprio(0);
  };

  const int NT = SEQ / 128;   // 16
  stageK_(0, K0);
  stageV_(0, V0);
  __syncthreads();
  stageK_(1, K1);
  qk(K0);
  for (int i = 0; i < NT; ++i) {
    int4v pa0[4], pa1[4];
    smpack(pa0, pa1);
    __syncthreads();
    if (i + 2 < NT) stageK_(i + 2, (i & 1) ? K1 : K0);
    if (i + 1 < NT) stageV_(i + 1, (i & 1) ? V0 : V1);
    if (i + 1 < NT) qk((i & 1) ? K0 : K1);
    pv((i & 1) ? V1 : V0, pa0, pa1);
  }

  int b = bh >> 4, h = bh & 15;
#pragma unroll
  for (int r = 0; r < 4; ++r) {
    float i0 = 1.0f / accs0[r];
    float i1 = 1.0f / accs1[r];
#pragma unroll
    for (int qh = 0; qh < 2; ++qh) {
      int srow_o = qt * 128 + wv * 32 + qh * 16 + g * 4 + r;
      float iv = qh ? i1 : i0;
#pragma unroll
      for (int nd = 0; nd < 4; ++nd) {
        int d = nd * 16 + cl;
        float val = (qh ? acc1[nd][r] : acc0[nd][r]) * iv;
        ctx[(((size_t)(b * SEQ + srow_o)) * NHEADS + h) * HDIM + d] = f2bf(val);
      }
    }
  }
}

// ---------------------------------------------------------------- launch
extern "C" void kernel_launch(void* const* d_in, const int* in_sizes, int n_in,
                              void* d_out, int out_size, void* d_ws, size_t ws_size,
                              hipStream_t stream) {
  (void)in_sizes; (void)n_in; (void)out_size; (void)ws_size;
  const float* query = (const float*)d_in[0];
  const float* key_  = (const float*)d_in[1];
  const float* value = (const float*)d_in[2];
  const float* Wq = (const float*)d_in[3];
  const float* bq = (const float*)d_in[4];
  const float* Wk = (const float*)d_in[5];
  const float* bk = (const float*)d_in[6];
  const float* Wv = (const float*)d_in[7];
  const float* bv = (const float*)d_in[8];
  const float* Wo = (const float*)d_in[9];
  const float* bo = (const float*)d_in[10];
  float* out = (float*)d_out;

  unsigned short* w = (unsigned short*)d_ws;
  const size_t NA = (size_t)MROWS * D_MODEL;    // 4M elems
  const size_t NW = (size_t)D_MODEL * D_MODEL;  // 1M elems
  unsigned short* Xq  = w;
  unsigned short* Xk  = Xq + NA;
  unsigned short* Xv  = Xk + NA;
  unsigned short* Wqb = Xv + NA;
  unsigned short* Wkb = Wqb + NW;
  unsigned short* Wvb = Wkb + NW;
  unsigned short* Wob = Wvb + NW;
  unsigned short* qs  = Wob + NW;     // [B,H,S,Dh]
  unsigned short* ks  = qs + NA;
  unsigned short* vtb = ks + NA;      // [B,H,Dh,S]  (written directly by gemm_qkv128)
  unsigned short* cx  = vtb + NA;     // [B,S,D]

  CvtArgs ca;
  ca.src[0] = query; ca.dst[0] = Xq;  ca.n[0] = (int)NA;
  ca.src[1] = key_;  ca.dst[1] = Xk;  ca.n[1] = (int)NA;
  ca.src[2] = value; ca.dst[2] = Xv;  ca.n[2] = (int)NA;
  ca.src[3] = Wq;    ca.dst[3] = Wqb; ca.n[3] = (int)NW;
  ca.src[4] = Wk;    ca.dst[4] = Wkb; ca.n[4] = (int)NW;
  ca.src[5] = Wv;    ca.dst[5] = Wvb; ca.n[5] = (int)NW;
  ca.src[6] = Wo;    ca.dst[6] = Wob; ca.n[6] = (int)NW;

  cvt_all<<<dim3(256, 7, 1), 256, 0, stream>>>(ca);
  gemm_qkv128<<<dim3(768, 1, 1), 512, 0, stream>>>(Xq, Xk, Xv, Wqb, Wkb, Wvb,
                                                   bq, bk, bv, qs, ks, vtb);
  attn<<<dim3(32, 16, 1), 256, 0, stream>>>(qs, ks, vtb, cx);
  gemm_out2<<<dim3(256, 1, 1), 512, 0, stream>>>(cx, Wob, bo, out);
}